// Round 3
// baseline (1370.073 us; speedup 1.0000x reference)
//
#include <hip/hip_runtime.h>
#include <hip/hip_bf16.h>

#define HID 128
#define IN_DIM 16

// ---------------- CSR build ----------------

__global__ __launch_bounds__(256) void count_k(const int* __restrict__ dst, int* __restrict__ deg, int E) {
    int e = blockIdx.x * 256 + threadIdx.x;
    if (e < E) atomicAdd(&deg[dst[e]], 1);
}

__global__ __launch_bounds__(1024) void scan_k(const int* __restrict__ deg, int* __restrict__ row_ptr, int n) {
    __shared__ int sbuf[1024];
    int t = threadIdx.x;
    int chunk = (n + 1023) / 1024;
    int base = t * chunk;
    int end = base + chunk; if (end > n) end = n;
    int s = 0;
    for (int i = base; i < end; i++) s += deg[i];
    sbuf[t] = s;
    __syncthreads();
    for (int off = 1; off < 1024; off <<= 1) {
        int add = (t >= off) ? sbuf[t - off] : 0;
        __syncthreads();
        sbuf[t] += add;
        __syncthreads();
    }
    int run = (t > 0) ? sbuf[t - 1] : 0;
    for (int i = base; i < end; i++) { row_ptr[i] = run; run += deg[i]; }
    if (end == n) row_ptr[n] = run;
}

__global__ __launch_bounds__(256) void fill_k(const int* __restrict__ src, const int* __restrict__ dst,
                                              const int* __restrict__ row_ptr, int* __restrict__ cnt,
                                              int* __restrict__ srcs, int E) {
    int e = blockIdx.x * 256 + threadIdx.x;
    if (e < E) {
        int d = dst[e];
        int p = row_ptr[d] + atomicAdd(&cnt[d], 1);
        srcs[p] = src[e];
    }
}

// ---------------- message aggregation ----------------

__global__ __launch_bounds__(128) void msg_k(const float* __restrict__ h, const int* __restrict__ row_ptr,
                                             const int* __restrict__ srcs, float* __restrict__ msg, int n) {
    int d = blockIdx.x;
    int t = threadIdx.x;
    int e = row_ptr[d], e1 = row_ptr[d + 1];
    float acc = 0.f;
    for (; e + 3 < e1; e += 4) {
        int s0 = srcs[e], s1 = srcs[e + 1], s2 = srcs[e + 2], s3 = srcs[e + 3];
        float v0 = h[(size_t)s0 * HID + t];
        float v1 = h[(size_t)s1 * HID + t];
        float v2 = h[(size_t)s2 * HID + t];
        float v3 = h[(size_t)s3 * HID + t];
        acc += v0 + v1 + v2 + v3;
    }
    for (; e < e1; e++) acc += h[(size_t)srcs[e] * HID + t];
    msg[(size_t)d * HID + t] = acc;
}

// ---------------- GEMM: C[n x 128] = act(A[n x KA] @ Wa + (B[n x 128] @ Wb) + extra) ----------------
// tile 64 nodes x 128 cols, 256 threads; thread = (tx: 4 cols, ty: 8 nodes)

template <int KA>
__device__ __forceinline__ void stage_tile(const float* __restrict__ A, int row0, int n, int tid,
                                           float (*sA)[72]) {
    constexpr int NQ = (64 * KA) / 1024;  // float4s per thread
#pragma unroll
    for (int q = 0; q < NQ; q++) {
        int idx = tid + q * 256;
        int node = idx & 63;
        int kslot = idx >> 6;
        int row = row0 + node;
        float4 v = make_float4(0.f, 0.f, 0.f, 0.f);
        if (row < n) v = *(const float4*)(A + (size_t)row * KA + kslot * 4);
        sA[kslot * 4 + 0][node] = v.x;
        sA[kslot * 4 + 1][node] = v.y;
        sA[kslot * 4 + 2][node] = v.z;
        sA[kslot * 4 + 3][node] = v.w;
    }
}

template <int KA>
__device__ __forceinline__ void mac_tile(const float* __restrict__ W, int tx, int ty,
                                         float acc[8][4], const float (*sA)[72]) {
    const float* wp = W + tx * 4;
#pragma unroll 4
    for (int k = 0; k < KA; k++) {
        float4 w = *(const float4*)(wp + (size_t)k * HID);
        float4 a0 = *(const float4*)&sA[k][ty * 8];
        float4 a1 = *(const float4*)&sA[k][ty * 8 + 4];
        float av[8] = {a0.x, a0.y, a0.z, a0.w, a1.x, a1.y, a1.z, a1.w};
#pragma unroll
        for (int m = 0; m < 8; m++) {
            acc[m][0] += av[m] * w.x;
            acc[m][1] += av[m] * w.y;
            acc[m][2] += av[m] * w.z;
            acc[m][3] += av[m] * w.w;
        }
    }
}

template <int KA, bool HAS_B, bool RELU>
__global__ __launch_bounds__(256) void gemm_k(const float* __restrict__ A, const float* __restrict__ Wa,
                                              const float* __restrict__ B, const float* __restrict__ Wb,
                                              const float* __restrict__ extra, float* __restrict__ C, int n) {
    __shared__ float sA[128][72];
    int tid = threadIdx.x;
    int tx = tid & 31, ty = tid >> 5;
    int row0 = blockIdx.x * 64;
    float acc[8][4];
    float4 ev = *(const float4*)(extra + tx * 4);
#pragma unroll
    for (int m = 0; m < 8; m++) { acc[m][0] = ev.x; acc[m][1] = ev.y; acc[m][2] = ev.z; acc[m][3] = ev.w; }

    stage_tile<KA>(A, row0, n, tid, sA);
    __syncthreads();
    mac_tile<KA>(Wa, tx, ty, acc, sA);
    if (HAS_B) {
        __syncthreads();
        stage_tile<HID>(B, row0, n, tid, sA);
        __syncthreads();
        mac_tile<HID>(Wb, tx, ty, acc, sA);
    }
#pragma unroll
    for (int m = 0; m < 8; m++) {
        int row = row0 + ty * 8 + m;
        if (row < n) {
            float4 o;
            o.x = RELU ? fmaxf(acc[m][0], 0.f) : acc[m][0];
            o.y = RELU ? fmaxf(acc[m][1], 0.f) : acc[m][1];
            o.z = RELU ? fmaxf(acc[m][2], 0.f) : acc[m][2];
            o.w = RELU ? fmaxf(acc[m][3], 0.f) : acc[m][3];
            *(float4*)(C + (size_t)row * HID + tx * 4) = o;
        }
    }
}

// ---------------- global representation ----------------

__global__ __launch_bounds__(128) void colsum_k(const float* __restrict__ h, float* __restrict__ gsum, int n) {
    int t = threadIdx.x;
    float acc = 0.f;
    for (int i = blockIdx.x; i < n; i += gridDim.x) acc += h[(size_t)i * HID + t];
    atomicAdd(&gsum[t], acc);
}

// grW[j] = b0[j] + sum_k rownorm(gsum)[k] * Wg[k*128+j]
__global__ __launch_bounds__(128) void grproj_k(const float* __restrict__ gsum, const float* __restrict__ Wg,
                                                const float* __restrict__ b, float* __restrict__ grW) {
    __shared__ float sg[HID];
    __shared__ float ws[2];
    int t = threadIdx.x;
    float g = gsum[t];
    float s = g * g;
#pragma unroll
    for (int off = 1; off < 64; off <<= 1) s += __shfl_xor(s, off);
    if ((t & 63) == 0) ws[t >> 6] = s;
    __syncthreads();
    float inv = 1.f / (sqrtf(ws[0] + ws[1]) + 1e-8f);
    sg[t] = g * inv;
    __syncthreads();
    float acc = b[t];
    for (int k = 0; k < HID; k++) acc += sg[k] * Wg[(size_t)k * HID + t];
    grW[t] = acc;
}

// ---------------- row-norm + has_in mask ----------------

__global__ __launch_bounds__(128) void norm_where_k(const float* __restrict__ t3, const int* __restrict__ deg,
                                                    float* __restrict__ h, int n) {
    int i = blockIdx.x;
    int t = threadIdx.x;
    float v = t3[(size_t)i * HID + t];
    float s = v * v;
#pragma unroll
    for (int off = 1; off < 64; off <<= 1) s += __shfl_xor(s, off);
    __shared__ float ws[2];
    if ((t & 63) == 0) ws[t >> 6] = s;
    __syncthreads();
    float out = v / (sqrtf(ws[0] + ws[1]) + 1e-8f);
    if (deg[i] > 0) h[(size_t)i * HID + t] = out;
}

// ---------------- launch ----------------

static inline char* align_up(char* p, size_t a) {
    return (char*)(((uintptr_t)p + a - 1) & ~(uintptr_t)(a - 1));
}

extern "C" void kernel_launch(void* const* d_in, const int* in_sizes, int n_in,
                              void* d_out, int out_size, void* d_ws, size_t ws_size,
                              hipStream_t stream) {
    const float* feat = (const float*)d_in[0];
    const int* src = (const int*)d_in[1];
    const int* dst = (const int*)d_in[2];
    const float* iW0 = (const float*)d_in[3];
    const float* ib0 = (const float*)d_in[4];
    const float* iW1 = (const float*)d_in[5];
    const float* ib1 = (const float*)d_in[6];
    const float* iW2 = (const float*)d_in[7];
    const float* ib2 = (const float*)d_in[8];
    const float* nW0 = (const float*)d_in[9];
    const float* nb0 = (const float*)d_in[10];
    const float* nW1 = (const float*)d_in[11];
    const float* nb1 = (const float*)d_in[12];
    const float* nW2 = (const float*)d_in[13];
    const float* nb2 = (const float*)d_in[14];

    int N = in_sizes[0] / IN_DIM;
    int E = in_sizes[1];
    int n_iter = in_sizes[10] / HID;
    float* h = (float*)d_out;

    char* w = (char*)d_ws;
    size_t big = (size_t)(N + 64) * HID * sizeof(float);
    float* msg = (float*)w; w += big;           // also reused as t3
    float* t1  = (float*)w; w += big;
    float* t2  = (float*)w; w += big;
    float* gsum = (float*)w; w += 1024;         // 128 floats used, 1 KiB reserved (r1 bug: was 256 B -> overlap)
    float* grW  = (float*)w; w += 1024;
    int* deg = (int*)w; w += (size_t)N * 4;  w = align_up(w, 16);
    int* row_ptr = (int*)w; w += (size_t)(N + 1) * 4;  w = align_up(w, 16);
    int* cnt = (int*)w; w += (size_t)N * 4;  w = align_up(w, 16);
    int* srcs = (int*)w; w += (size_t)E * 4;
    (void)ws_size; (void)n_in; (void)out_size;

    hipMemsetAsync(deg, 0, (size_t)N * 4, stream);
    hipMemsetAsync(cnt, 0, (size_t)N * 4, stream);
    hipMemsetAsync(gsum, 0, HID * 4, stream);

    int eg = (E + 255) / 256;
    count_k<<<eg, 256, 0, stream>>>(dst, deg, E);
    scan_k<<<1, 1024, 0, stream>>>(deg, row_ptr, N);
    fill_k<<<eg, 256, 0, stream>>>(src, dst, row_ptr, cnt, srcs, E);

    int gb = (N + 63) / 64;
    // init MLP: feat -> t1 -> t2 -> h
    gemm_k<IN_DIM, false, true ><<<gb, 256, 0, stream>>>(feat, iW0, nullptr, nullptr, ib0, t1, N);
    gemm_k<HID,    false, true ><<<gb, 256, 0, stream>>>(t1,   iW1, nullptr, nullptr, ib1, t2, N);
    gemm_k<HID,    false, false><<<gb, 256, 0, stream>>>(t2,   iW2, nullptr, nullptr, ib2, h,  N);
    colsum_k<<<512, HID, 0, stream>>>(h, gsum, N);

    for (int i = 0; i < n_iter; i++) {
        const float* W0 = nW0 + (size_t)i * 3 * HID * HID;
        grproj_k<<<1, HID, 0, stream>>>(gsum, W0 + 2 * HID * HID, nb0 + (size_t)i * HID, grW);
        msg_k<<<N, HID, 0, stream>>>(h, row_ptr, srcs, msg, N);
        gemm_k<HID, true,  true ><<<gb, 256, 0, stream>>>(msg, W0, h, W0 + HID * HID, grW, t1, N);
        gemm_k<HID, false, true ><<<gb, 256, 0, stream>>>(t1, nW1 + (size_t)i * HID * HID, nullptr, nullptr,
                                                          nb1 + (size_t)i * HID, t2, N);
        gemm_k<HID, false, false><<<gb, 256, 0, stream>>>(t2, nW2 + (size_t)i * HID * HID, nullptr, nullptr,
                                                          nb2 + (size_t)i * HID, msg, N);
        norm_where_k<<<N, HID, 0, stream>>>(msg, deg, h, N);
        if (i + 1 < n_iter) {
            hipMemsetAsync(gsum, 0, HID * 4, stream);
            colsum_k<<<512, HID, 0, stream>>>(h, gsum, N);
        }
    }
}

// Round 4
// 791.388 us; speedup vs baseline: 1.7312x; 1.7312x over previous
//
#include <hip/hip_runtime.h>
#include <hip/hip_bf16.h>

#define HID 128
#define IN_DIM 16
#define LDST 136  // LDS row stride in bf16 elems: 272 B -> bank-rotation 4/lane, 16B-aligned rows

typedef unsigned short u16;
typedef __attribute__((ext_vector_type(8))) short short8;
typedef __attribute__((ext_vector_type(4))) float f32x4;

__device__ __forceinline__ float bf2f(u16 u) { return __uint_as_float(((unsigned)u) << 16); }
__device__ __forceinline__ u16 f2b(float f) {  // RNE
    unsigned u = __float_as_uint(f);
    return (u16)((u + 0x7FFF + ((u >> 16) & 1)) >> 16);
}

// ---------------- CSR build ----------------

__global__ __launch_bounds__(256) void count_k(const int* __restrict__ dst, int* __restrict__ deg, int E) {
    int e = blockIdx.x * 256 + threadIdx.x;
    if (e < E) atomicAdd(&deg[dst[e]], 1);
}

__global__ __launch_bounds__(1024) void scan_k(const int* __restrict__ deg, int* __restrict__ row_ptr, int n) {
    __shared__ int sbuf[1024];
    int t = threadIdx.x;
    int chunk = (n + 1023) / 1024;
    int base = t * chunk;
    int end = base + chunk; if (end > n) end = n;
    int s = 0;
    for (int i = base; i < end; i++) s += deg[i];
    sbuf[t] = s;
    __syncthreads();
    for (int off = 1; off < 1024; off <<= 1) {
        int add = (t >= off) ? sbuf[t - off] : 0;
        __syncthreads();
        sbuf[t] += add;
        __syncthreads();
    }
    int run = (t > 0) ? sbuf[t - 1] : 0;
    for (int i = base; i < end; i++) { row_ptr[i] = run; run += deg[i]; }
    if (end == n) row_ptr[n] = run;
}

__global__ __launch_bounds__(256) void fill_k(const int* __restrict__ src, const int* __restrict__ dst,
                                              const int* __restrict__ row_ptr, int* __restrict__ cnt,
                                              int* __restrict__ srcs, int E) {
    int e = blockIdx.x * 256 + threadIdx.x;
    if (e < E) {
        int d = dst[e];
        int p = row_ptr[d] + atomicAdd(&cnt[d], 1);
        srcs[p] = src[e];
    }
}

// ---------------- weight prep: fp32 [K,128] -> bf16 [128][K] (n-major) ----------------

struct WJobs {
    const float* src[16];
    int dstoff[16];
    int ks[16];  // log2 K
};

__global__ __launch_bounds__(256) void wprep_k(WJobs j, u16* __restrict__ Wt) {
    int m = blockIdx.x;
    const float* s = j.src[m];
    u16* d = Wt + j.dstoff[m];
    int ks = j.ks[m];
    int K = 1 << ks;
    int tot = K * HID;
    for (int idx = threadIdx.x; idx < tot; idx += 256) {
        int nn = idx >> ks;
        int kk = idx & (K - 1);
        d[idx] = f2b(s[kk * HID + nn]);  // writes coalesced, reads L2-cached
    }
}

// ---------------- message aggregation: gather bf16 h rows, wave per dst ----------------

__global__ __launch_bounds__(256) void msg_k(const u16* __restrict__ hb, const int* __restrict__ row_ptr,
                                             const int* __restrict__ srcs, u16* __restrict__ msgb, int n) {
    int wave = threadIdx.x >> 6, lane = threadIdx.x & 63;
    int d = blockIdx.x * 4 + wave;
    if (d >= n) return;
    int e = row_ptr[d], e1 = row_ptr[d + 1];
    float a0 = 0.f, a1 = 0.f;
    for (; e + 3 < e1; e += 4) {
        int s0 = srcs[e], s1 = srcs[e + 1], s2 = srcs[e + 2], s3 = srcs[e + 3];
        unsigned v0 = *(const unsigned*)(hb + (size_t)s0 * HID + lane * 2);
        unsigned v1 = *(const unsigned*)(hb + (size_t)s1 * HID + lane * 2);
        unsigned v2 = *(const unsigned*)(hb + (size_t)s2 * HID + lane * 2);
        unsigned v3 = *(const unsigned*)(hb + (size_t)s3 * HID + lane * 2);
        a0 += __uint_as_float(v0 << 16) + __uint_as_float(v1 << 16) +
              __uint_as_float(v2 << 16) + __uint_as_float(v3 << 16);
        a1 += __uint_as_float(v0 & 0xffff0000u) + __uint_as_float(v1 & 0xffff0000u) +
              __uint_as_float(v2 & 0xffff0000u) + __uint_as_float(v3 & 0xffff0000u);
    }
    for (; e < e1; e++) {
        unsigned v = *(const unsigned*)(hb + (size_t)srcs[e] * HID + lane * 2);
        a0 += __uint_as_float(v << 16);
        a1 += __uint_as_float(v & 0xffff0000u);
    }
    unsigned out = (unsigned)f2b(a0) | ((unsigned)f2b(a1) << 16);
    *(unsigned*)(msgb + (size_t)d * HID + lane * 2) = out;
}

// ---------------- MFMA GEMM: C[64 x 128] tile, 4 waves (2x2), 16x16x32 bf16 ----------------

__device__ __forceinline__ void stageA128(const u16* __restrict__ A, int row0, int tid, u16* sA) {
#pragma unroll
    for (int q = 0; q < 4; q++) {
        int c = tid + q * 256;
        int row = c >> 4, j8 = c & 15;
        uint4 v = *(const uint4*)(A + (size_t)(row0 + row) * HID + j8 * 8);
        *(uint4*)(sA + row * LDST + j8 * 8) = v;
    }
}

__device__ __forceinline__ void stageW128(const u16* __restrict__ Wt, int tid, u16* sB) {
#pragma unroll
    for (int q = 0; q < 8; q++) {
        int c = tid + q * 256;
        int row = c >> 4, j8 = c & 15;
        uint4 v = *(const uint4*)(Wt + row * HID + j8 * 8);
        *(uint4*)(sB + row * LDST + j8 * 8) = v;
    }
}

__device__ __forceinline__ void stageFeat(const float* __restrict__ feat, int row0, int n, int tid, u16* sA) {
    int row = tid >> 2, coff = tid & 3;
    ushort4 o = make_ushort4(0, 0, 0, 0);
    if (row0 + row < n) {
        float4 v = *(const float4*)(feat + (size_t)(row0 + row) * IN_DIM + coff * 4);
        o = make_ushort4(f2b(v.x), f2b(v.y), f2b(v.z), f2b(v.w));
    }
    *(ushort4*)(sA + row * LDST + coff * 4) = o;
    *(ushort4*)(sA + row * LDST + 16 + coff * 4) = make_ushort4(0, 0, 0, 0);  // zero-pad K 16->32
}

__device__ __forceinline__ void stageW16(const u16* __restrict__ Wt, int tid, u16* sB) {
    int row = tid >> 1, h8 = tid & 1;
    uint4 v = *(const uint4*)(Wt + row * IN_DIM + h8 * 8);
    *(uint4*)(sB + row * LDST + h8 * 8) = v;
    *(uint4*)(sB + row * LDST + 16 + h8 * 8) = make_uint4(0, 0, 0, 0);
}

template <int KSTEPS>
__device__ __forceinline__ void mac(const u16* sA, const u16* sB, int wrow, int wcol,
                                    int ln15, int quad, f32x4 acc[2][4]) {
#pragma unroll
    for (int kk = 0; kk < KSTEPS; kk++) {
        short8 a[2], b[4];
#pragma unroll
        for (int mi = 0; mi < 2; mi++)
            a[mi] = *(const short8*)(sA + (wrow + mi * 16 + ln15) * LDST + kk * 32 + quad * 8);
#pragma unroll
        for (int ni = 0; ni < 4; ni++)
            b[ni] = *(const short8*)(sB + (wcol + ni * 16 + ln15) * LDST + kk * 32 + quad * 8);
#pragma unroll
        for (int mi = 0; mi < 2; mi++)
#pragma unroll
            for (int ni = 0; ni < 4; ni++)
                acc[mi][ni] = __builtin_amdgcn_mfma_f32_16x16x32_bf16(a[mi], b[ni], acc[mi][ni], 0, 0, 0);
    }
}

// MODE 0: A = feat fp32 [n,16]; MODE 1: A = bf16 [n,128]; MODE 2: dual K (A@Wt + A2@Wt2)
template <int MODE, bool RELU, bool OUTF, bool OUTB>
__global__ __launch_bounds__(256) void mgemm_k(const void* __restrict__ Araw, const u16* __restrict__ Wt,
                                               const u16* __restrict__ A2, const u16* __restrict__ Wt2,
                                               const float* __restrict__ bias, float* __restrict__ Cf,
                                               u16* __restrict__ Cb, int n) {
    __shared__ u16 sA[64 * LDST];
    __shared__ u16 sB[128 * LDST];
    int tid = threadIdx.x;
    int lane = tid & 63, wave = tid >> 6;
    int ln15 = lane & 15, quad = lane >> 4;
    int wrow = (wave >> 1) * 32, wcol = (wave & 1) * 64;
    int row0 = blockIdx.x * 64;

    f32x4 acc[2][4];
#pragma unroll
    for (int ni = 0; ni < 4; ni++) {
        float bv = bias[wcol + ni * 16 + ln15];
#pragma unroll
        for (int mi = 0; mi < 2; mi++) acc[mi][ni] = (f32x4){bv, bv, bv, bv};
    }

    if (MODE == 0) {
        stageFeat((const float*)Araw, row0, n, tid, sA);
        stageW16(Wt, tid, sB);
        __syncthreads();
        mac<1>(sA, sB, wrow, wcol, ln15, quad, acc);
    } else {
        stageA128((const u16*)Araw, row0, tid, sA);
        stageW128(Wt, tid, sB);
        __syncthreads();
        mac<4>(sA, sB, wrow, wcol, ln15, quad, acc);
        if (MODE == 2) {
            __syncthreads();
            stageA128(A2, row0, tid, sA);
            stageW128(Wt2, tid, sB);
            __syncthreads();
            mac<4>(sA, sB, wrow, wcol, ln15, quad, acc);
        }
    }

    // epilogue: C/D layout col=lane&15, row=quad*4+reg  [m89-verified]
#pragma unroll
    for (int mi = 0; mi < 2; mi++)
#pragma unroll
        for (int r = 0; r < 4; r++) {
            int row = row0 + wrow + mi * 16 + quad * 4 + r;
            if (row < n) {
#pragma unroll
                for (int ni = 0; ni < 4; ni++) {
                    float v = acc[mi][ni][r];
                    if (RELU) v = fmaxf(v, 0.f);
                    int col = wcol + ni * 16 + ln15;
                    if (OUTF) Cf[(size_t)row * HID + col] = v;
                    if (OUTB) Cb[(size_t)row * HID + col] = f2b(v);
                }
            }
        }
}

// ---------------- global representation ----------------

__global__ __launch_bounds__(128) void colsum_k(const float* __restrict__ h, float* __restrict__ gsum, int n) {
    int t = threadIdx.x;
    float acc = 0.f;
    for (int i = blockIdx.x; i < n; i += gridDim.x) acc += h[(size_t)i * HID + t];
    atomicAdd(&gsum[t], acc);
}

__global__ __launch_bounds__(128) void grproj_k(const float* __restrict__ gsum, const float* __restrict__ Wg,
                                                const float* __restrict__ b, float* __restrict__ grW) {
    __shared__ float sg[HID];
    __shared__ float ws[2];
    int t = threadIdx.x;
    float g = gsum[t];
    float s = g * g;
#pragma unroll
    for (int off = 1; off < 64; off <<= 1) s += __shfl_xor(s, off);
    if ((t & 63) == 0) ws[t >> 6] = s;
    __syncthreads();
    float inv = 1.f / (sqrtf(ws[0] + ws[1]) + 1e-8f);
    sg[t] = g * inv;
    __syncthreads();
    float acc = b[t];
    for (int k = 0; k < HID; k++) acc += sg[k] * Wg[(size_t)k * HID + t];
    grW[t] = acc;
}

// ---------------- row-norm + has_in mask (wave per row) ----------------

__global__ __launch_bounds__(256) void norm_where_k(const float* __restrict__ t3, const int* __restrict__ deg,
                                                    float* __restrict__ h, u16* __restrict__ hb, int n) {
    int wave = threadIdx.x >> 6, lane = threadIdx.x & 63;
    int r = blockIdx.x * 4 + wave;
    if (r >= n) return;
    float2 v = *(const float2*)(t3 + (size_t)r * HID + lane * 2);
    float s = v.x * v.x + v.y * v.y;
#pragma unroll
    for (int off = 1; off < 64; off <<= 1) s += __shfl_xor(s, off);
    if (deg[r] > 0) {
        float inv = 1.f / (sqrtf(s) + 1e-8f);
        float2 o = {v.x * inv, v.y * inv};
        *(float2*)(h + (size_t)r * HID + lane * 2) = o;
        unsigned pb = (unsigned)f2b(o.x) | ((unsigned)f2b(o.y) << 16);
        *(unsigned*)(hb + (size_t)r * HID + lane * 2) = pb;
    }
}

// ---------------- launch ----------------

static inline char* align_up(char* p, size_t a) {
    return (char*)(((uintptr_t)p + a - 1) & ~(uintptr_t)(a - 1));
}

extern "C" void kernel_launch(void* const* d_in, const int* in_sizes, int n_in,
                              void* d_out, int out_size, void* d_ws, size_t ws_size,
                              hipStream_t stream) {
    const float* feat = (const float*)d_in[0];
    const int* src = (const int*)d_in[1];
    const int* dst = (const int*)d_in[2];
    const float* iW0 = (const float*)d_in[3];
    const float* ib0 = (const float*)d_in[4];
    const float* iW1 = (const float*)d_in[5];
    const float* ib1 = (const float*)d_in[6];
    const float* iW2 = (const float*)d_in[7];
    const float* ib2 = (const float*)d_in[8];
    const float* nW0 = (const float*)d_in[9];
    const float* nb0 = (const float*)d_in[10];
    const float* nW1 = (const float*)d_in[11];
    const float* nb1 = (const float*)d_in[12];
    const float* nW2 = (const float*)d_in[13];
    const float* nb2 = (const float*)d_in[14];

    int N = in_sizes[0] / IN_DIM;
    int E = in_sizes[1];
    int n_iter = in_sizes[10] / HID;
    float* h = (float*)d_out;

    char* w = (char*)d_ws;
    size_t big4 = (size_t)(N + 64) * HID * sizeof(float);
    size_t big2 = (size_t)(N + 64) * HID * sizeof(u16);
    float* t3 = (float*)w; w += big4;
    u16* hb   = (u16*)w; w += big2;
    u16* msgb = (u16*)w; w += big2;
    u16* t1b  = (u16*)w; w += big2;
    u16* t2b  = (u16*)w; w += big2;
    float* gsum = (float*)w; w += 1024;
    float* grW  = (float*)w; w += 1024;
    u16* Wt = (u16*)w; w += (size_t)(2048 + 2 * 16384 + n_iter * 4 * 16384) * sizeof(u16);
    w = align_up(w, 16);
    int* deg = (int*)w; w += (size_t)N * 4;  w = align_up(w, 16);
    int* row_ptr = (int*)w; w += (size_t)(N + 1) * 4;  w = align_up(w, 16);
    int* cnt = (int*)w; w += (size_t)N * 4;  w = align_up(w, 16);
    int* srcs = (int*)w; w += (size_t)E * 4;
    (void)ws_size; (void)n_in; (void)out_size;

    // Wt layout offsets (bf16 elems)
    const int OFF_IW0 = 0;
    const int OFF_IW1 = 2048;
    const int OFF_IW2 = 2048 + 16384;
    const int OFF_IT = 2048 + 2 * 16384;  // per iter: W0a, W0b, W1, W2 (4 x 16384)

    WJobs jobs;
    int nj = 0;
    jobs.src[nj] = iW0; jobs.dstoff[nj] = OFF_IW0; jobs.ks[nj] = 4; nj++;
    jobs.src[nj] = iW1; jobs.dstoff[nj] = OFF_IW1; jobs.ks[nj] = 7; nj++;
    jobs.src[nj] = iW2; jobs.dstoff[nj] = OFF_IW2; jobs.ks[nj] = 7; nj++;
    for (int i = 0; i < n_iter && nj + 4 <= 16; i++) {
        int base = OFF_IT + i * 4 * 16384;
        jobs.src[nj] = nW0 + (size_t)i * 3 * HID * HID;               jobs.dstoff[nj] = base;             jobs.ks[nj] = 7; nj++;
        jobs.src[nj] = nW0 + (size_t)i * 3 * HID * HID + HID * HID;   jobs.dstoff[nj] = base + 16384;     jobs.ks[nj] = 7; nj++;
        jobs.src[nj] = nW1 + (size_t)i * HID * HID;                   jobs.dstoff[nj] = base + 2 * 16384; jobs.ks[nj] = 7; nj++;
        jobs.src[nj] = nW2 + (size_t)i * HID * HID;                   jobs.dstoff[nj] = base + 3 * 16384; jobs.ks[nj] = 7; nj++;
    }

    hipMemsetAsync(deg, 0, (size_t)N * 4, stream);
    hipMemsetAsync(cnt, 0, (size_t)N * 4, stream);
    hipMemsetAsync(gsum, 0, HID * 4, stream);

    wprep_k<<<nj, 256, 0, stream>>>(jobs, Wt);

    int eg = (E + 255) / 256;
    count_k<<<eg, 256, 0, stream>>>(dst, deg, E);
    scan_k<<<1, 1024, 0, stream>>>(deg, row_ptr, N);
    fill_k<<<eg, 256, 0, stream>>>(src, dst, row_ptr, cnt, srcs, E);

    int gb = (N + 63) / 64;
    int rb = (N + 3) / 4;
    // init MLP: feat -> t1b -> t2b -> h (+hb)
    mgemm_k<0, true,  false, true ><<<gb, 256, 0, stream>>>(feat, Wt + OFF_IW0, nullptr, nullptr, ib0, nullptr, t1b, N);
    mgemm_k<1, true,  false, true ><<<gb, 256, 0, stream>>>(t1b,  Wt + OFF_IW1, nullptr, nullptr, ib1, nullptr, t2b, N);
    mgemm_k<1, false, true,  true ><<<gb, 256, 0, stream>>>(t2b,  Wt + OFF_IW2, nullptr, nullptr, ib2, h, hb, N);
    colsum_k<<<512, HID, 0, stream>>>(h, gsum, N);

    for (int i = 0; i < n_iter; i++) {
        const u16* Wit = Wt + OFF_IT + (size_t)i * 4 * 16384;
        const float* Wg = nW0 + (size_t)i * 3 * HID * HID + 2 * HID * HID;
        grproj_k<<<1, HID, 0, stream>>>(gsum, Wg, nb0 + (size_t)i * HID, grW);
        msg_k<<<rb, 256, 0, stream>>>(hb, row_ptr, srcs, msgb, N);
        mgemm_k<2, true,  false, true ><<<gb, 256, 0, stream>>>(msgb, Wit, hb, Wit + 16384, grW, nullptr, t1b, N);
        mgemm_k<1, true,  false, true ><<<gb, 256, 0, stream>>>(t1b, Wit + 2 * 16384, nullptr, nullptr,
                                                                nb1 + (size_t)i * HID, nullptr, t2b, N);
        mgemm_k<1, false, true,  false><<<gb, 256, 0, stream>>>(t2b, Wit + 3 * 16384, nullptr, nullptr,
                                                                nb2 + (size_t)i * HID, t3, nullptr, N);
        norm_where_k<<<rb, 256, 0, stream>>>(t3, deg, h, hb, N);
        if (i + 1 < n_iter) {
            hipMemsetAsync(gsum, 0, HID * 4, stream);
            colsum_k<<<512, HID, 0, stream>>>(h, gsum, N);
        }
    }
}